// Round 4
// baseline (665.744 us; speedup 1.0000x reference)
//
#include <hip/hip_runtime.h>
#include <cstddef>
#include <cstdint>

// Problem constants: EMBED=1024, NUM_HEADS=16, GQA=4, KV_HEADS=4,
// HEAD_DIM=64, KV_EMBED=256, EPS=1e-3, B=2, T=1024.
#define TSEQ 1024

typedef __attribute__((ext_vector_type(8))) short short8;   // 8 bf16 = 4 VGPRs
typedef __attribute__((ext_vector_type(4))) float floatx4;  // MFMA acc

// Workspace layout (floats):
//  XQ : 2048 x 1024  (2M)
//  XK : 2048 x 256   (0.5M)
//  XVt: 2 x 256 x 1024 (0.5M)  -- V-projection TRANSPOSED: [b][h*64+c][j]
//  XO : 2048 x 1024  (2M)
//  P  : 32 x 1024x1024 (33.55M) -- probs/phi in DIAGONAL layout (see below)
static constexpr size_t OFF_XQ  = 0;
static constexpr size_t OFF_XK  = (size_t)2 * 1024 * 1024;
static constexpr size_t OFF_XVT = OFF_XK + (size_t)512 * 1024;
static constexpr size_t OFF_XO  = OFF_XVT + (size_t)512 * 1024;
static constexpr size_t OFF_P   = OFF_XO + (size_t)2 * 1024 * 1024;

// DIAGONAL LAYOUT (R7): logical cell (r, c) of each z's 1024x1024 matrix is
// stored at Pw[(r + (c>>4)) & 1023][c]. The monotonic-recurrence wavefront
// (lane t owns cols [16t,16t+16), processes row r = s - t at step s) reads
// and writes ONE contiguous 4KB storage row (s & 1023) per step, in place.
// The mod-1024 wrap is a bijection: blocks overwritten at step m (lanes
// t <= m) are exactly the blocks NOT consumed at step m+1024 (lanes t > m).
// Scores writes C and PV reads A through the same (row + (col>>4)) & 1023
// shift; both keep their original per-instruction coalescing.
//
// R9 diagnosis history: R7 (global loads/step) and R8 (LDS-staged loads,
// stores only per step) BOTH measured ~730 cy/step -> the stall is the
// per-step STORE: a single phi[16] buffer is stored then rewritten next
// step, so the compiler inserts s_waitcnt vmcnt() before the WAW register
// reuse, exposing ~500cy store latency each step. Fix A: 4-deep phi
// register rotation (reuse distance ~3 steps). Fix B: affine split
// phi[c] = SA[c]*phiIn + SB[c]; SA/H0/sa15h0 precomputed one step ahead
// from prefetched p; SB (scan of b) runs parallel to the phiL shuffle;
// serial cross-step path = shuffle + ONE fma.

// ---------------------------------------------------------------------------
// fp32 -> bf16 hi/lo split (RNE). x ≈ hi + lo with residual ~2^-17 |x|.
// ---------------------------------------------------------------------------
__device__ __forceinline__ void cvt_hi_lo(float x, unsigned short& hi,
                                          unsigned short& lo) {
  unsigned u = __float_as_uint(x);
  unsigned rh = (u + 0x7FFFu + ((u >> 16) & 1u)) & 0xFFFF0000u;
  hi = (unsigned short)(rh >> 16);
  float xl = x - __uint_as_float(rh);
  unsigned ul = __float_as_uint(xl);
  unsigned rl = ul + 0x7FFFu + ((ul >> 16) & 1u);
  lo = (unsigned short)(rl >> 16);
}

// ---------------------------------------------------------------------------
// Unified NT GEMM core, MFMA bf16x3 (R5-proven).
// ADIAG: A row index gets + (k>>4) & 1023 (reads diagonal-layout matrix).
// CDIAG: C row index gets + (col>>4) & 1023 (writes diagonal-layout matrix).
// ---------------------------------------------------------------------------
template <int EPI, int ADIAG, int CDIAG>
__device__ __forceinline__ void mfma_nt_core(
    const float* __restrict__ A, int lda,
    const float* __restrict__ B, int ldb,
    float* __restrict__ C, int ldc, int K,
    const float* __restrict__ bias)
{
  __shared__ __align__(16) unsigned short Ah[64][40];
  __shared__ __align__(16) unsigned short Al[64][40];
  __shared__ __align__(16) unsigned short Bh[64][40];
  __shared__ __align__(16) unsigned short Bl[64][40];

  const int bm = blockIdx.y << 6;
  const int bn = blockIdx.x << 6;
  const int tid  = threadIdx.x;
  const int lane = tid & 63;
  const int wave = tid >> 6;        // 0..3 -> row sub-tile
  const int m16  = lane & 15;
  const int quad = lane >> 4;

  const int srow = tid >> 2;        // staging: row 0..63
  const int skq  = (tid & 3) << 3;  // staging: k offset 0,8,16,24

  floatx4 acc[4];
#pragma unroll
  for (int c = 0; c < 4; ++c) acc[c] = (floatx4){0.f, 0.f, 0.f, 0.f};

  for (int k0 = 0; k0 < K; k0 += 32) {
    {
      const int kq = k0 + skq;
      int arow = bm + srow;
      if (ADIAG) arow = (arow + (kq >> 4)) & 1023;
      const float* ap = A + (size_t)arow * lda + kq;
      const float* bp = B + (size_t)(bn + srow) * ldb + kq;
      float av[8] __attribute__((aligned(16)));
      float bv[8] __attribute__((aligned(16)));
      *(float4*)&av[0] = *(const float4*)(ap);
      *(float4*)&av[4] = *(const float4*)(ap + 4);
      *(float4*)&bv[0] = *(const float4*)(bp);
      *(float4*)&bv[4] = *(const float4*)(bp + 4);
      short8 vah, valo, vbh, vblo;
#pragma unroll
      for (int e = 0; e < 8; ++e) {
        unsigned short h, l;
        cvt_hi_lo(av[e], h, l);
        vah[e] = (short)h; valo[e] = (short)l;
        cvt_hi_lo(bv[e], h, l);
        vbh[e] = (short)h; vblo[e] = (short)l;
      }
      *(short8*)&Ah[srow][skq] = vah;
      *(short8*)&Al[srow][skq] = valo;
      *(short8*)&Bh[srow][skq] = vbh;
      *(short8*)&Bl[srow][skq] = vblo;
    }
    __syncthreads();

    const int arow = (wave << 4) + m16;
    const short8 a_h = *(const short8*)&Ah[arow][quad << 3];
    const short8 a_l = *(const short8*)&Al[arow][quad << 3];
#pragma unroll
    for (int c = 0; c < 4; ++c) {
      const int brow = (c << 4) + m16;
      const short8 b_h = *(const short8*)&Bh[brow][quad << 3];
      const short8 b_l = *(const short8*)&Bl[brow][quad << 3];
      acc[c] = __builtin_amdgcn_mfma_f32_16x16x32_bf16(a_h, b_h, acc[c], 0, 0, 0);
      acc[c] = __builtin_amdgcn_mfma_f32_16x16x32_bf16(a_h, b_l, acc[c], 0, 0, 0);
      acc[c] = __builtin_amdgcn_mfma_f32_16x16x32_bf16(a_l, b_h, acc[c], 0, 0, 0);
    }
    __syncthreads();
  }

#pragma unroll
  for (int c = 0; c < 4; ++c) {
#pragma unroll
    for (int r = 0; r < 4; ++r) {
      const int row = (wave << 4) + (quad << 2) + r;
      const int col = (c << 4) + m16;
      float v = acc[c][r];
      if (EPI == 0) { if (bias) v += bias[bn + col]; }
      if (EPI == 1) { v += bias[bm + row]; }
      if (EPI == 2) {
        v = 1.0f / (1.0f + expf(-v));
        v = fminf(fmaxf(v, 0.001f), 0.999f);
      }
      int crow = bm + row;
      if (CDIAG) crow = (crow + ((bn + col) >> 4)) & 1023;
      C[(size_t)crow * ldc + (bn + col)] = v;
    }
  }
}

__global__ __launch_bounds__(256) void gemm_nt_mfma_k(
    const float* __restrict__ A, int lda, const float* __restrict__ W, int ldw,
    const float* __restrict__ bias, float* __restrict__ C, int ldc, int K)
{
  mfma_nt_core<0, 0, 0>(A, lda, W, ldw, C, ldc, K, bias);
}

__global__ __launch_bounds__(256) void proj_vt_k(
    const float* __restrict__ vw, const float* __restrict__ value,
    const float* __restrict__ vb, float* __restrict__ XVt)
{
  const int b = blockIdx.z;
  mfma_nt_core<1, 0, 0>(vw, 1024, value + ((size_t)b << 20), 1024,
                        XVt + (size_t)b * 256 * 1024, 1024, 1024, vb);
}

// scores: writes P in DIAGONAL layout (CDIAG=1)
__global__ __launch_bounds__(256) void scores_mfma_k(
    const float* __restrict__ XQ, const float* __restrict__ XK,
    float* __restrict__ P)
{
  const int z = blockIdx.z;
  const int b = z >> 4;
  mfma_nt_core<2, 0, 1>(XQ + ((size_t)b << 20) + ((size_t)(z & 15) << 6), 1024,
                        XK + (size_t)b * TSEQ * 256 + ((size_t)(z & 3) << 6), 256,
                        P + ((size_t)z << 20), 1024, 64, nullptr);
}

// pv: reads phi (A matrix) from DIAGONAL layout (ADIAG=1)
__global__ __launch_bounds__(256) void pv_mfma_k(
    const float* __restrict__ P, const float* __restrict__ XVt,
    float* __restrict__ XO)
{
  const int z = blockIdx.z;
  const int b = z >> 4;
  mfma_nt_core<0, 1, 0>(P + ((size_t)z << 20), 1024,
                        XVt + (size_t)b * 256 * 1024 + (size_t)(z & 3) * 64 * 1024, 1024,
                        XO + ((size_t)b << 20) + ((size_t)(z & 15) << 6), 1024,
                        1024, nullptr);
}

// ---------------------------------------------------------------------------
// global -> LDS direct (16B per lane). gp is PER-LANE; lds dest is uniform
// base + lane*16 (hardware rule). Our layout is linear so this matches.
// ---------------------------------------------------------------------------
__device__ __forceinline__ void glds16(const float* gp, float* lp) {
  __builtin_amdgcn_global_load_lds(
      (const __attribute__((address_space(1))) unsigned int*)gp,
      (__attribute__((address_space(3))) unsigned int*)lp,
      16, 0, 0);
}

// ---------------------------------------------------------------------------
// Monotonic recurrence, DIAGONAL-WAVEFRONT systolic (R9).
// ONE WAVE per z. Lane t owns cols [16t,16t+16); at step s processes row
// r = s - t:  phi[c] = SA[c]*phiIn + SB[c],
//   phiIn = H0*phiL (phiL = neighbor's phi15, shuffled),
//   H0 = 1 - pL (neighbor's p15, shuffled ONE STEP EARLY),
//   SA[c] = prefix-prod of (1-p[c-1]) (precomputed one step early),
//   SB[c] = scan of b with same coeffs (b = prev-row carry; runs parallel
//           to the phiL shuffle),
//   phi15 = fmaf(sa15h0, phiL, SB15)  -- ONE fma after the shuffle.
// p staged via global_load_lds in 8-row chunks (double buffer, one vmcnt
// drain per chunk, R8-proven). phi stores rotate over 4 register buffers
// (Ph[j&3], static idx via unroll) so the compiler's store-WAW vmcnt wait
// is satisfied ~3 steps (~500cy) before register reuse.
// Cross-lane = __shfl only (DPP failed 3x on gfx950 -- permanently banned).
// ---------------------------------------------------------------------------
#define CHUNK 8
#define NCHUNK 136   // 136*8 = 1088 steps (last step is all-invalid pad)

__global__ __launch_bounds__(64) void mono_rec_k(float* __restrict__ P)
{
  const int z = blockIdx.x;
  float* __restrict__ Pz = P + ((size_t)z << 20);
  const int t = threadIdx.x;     // lane 0..63
  const int col0 = t << 4;       // first owned column

  __shared__ __align__(16) float Lb[2][CHUNK * 1024];   // 2 x 32 KB

  float b[16];                   // carry: b[c] = phi[r-1,c] * p[r-1,c]
#pragma unroll
  for (int c = 0; c < 16; ++c) b[c] = 0.0f;
  float phi15h = 0.0f;           // own phi[15], held for lane t+1's shuffle

  float Ph[4][16];               // 4-deep phi store rotation
  float Pp[2][16];               // p row, double-buffered (j&1)
  float Hh[2][16];               // H coeffs: Hh[.][0]=H0, Hh[.][c]=1-p[c-1]
  float Sa[2][16];               // prefix products of Hh (Sa[.][0]=1)
  float sa15h0[2];               // Sa[15]*H0 (critical-path fused coeff)
#pragma unroll
  for (int c = 0; c < 16; ++c) { Pp[0][c] = 0.0f; Pp[1][c] = 0.0f; }

  // precompute step-state for slot `sl` from LDS row `lrow`; prevP15 is the
  // p[15] of the PREVIOUS step (feeds the early pL shuffle -> H0).
  auto precomp = [&](int sl, const float* lrow, float prevP15) {
#pragma unroll
    for (int q = 0; q < 4; ++q)
      *(float4*)&Pp[sl][4 * q] = *(const float4*)(lrow + 4 * q);
    const float pLn = __shfl_up(prevP15, 1);
    Hh[sl][0] = (t == 0) ? 0.0f : (1.0f - pLn);
#pragma unroll
    for (int c = 1; c < 16; ++c) Hh[sl][c] = 1.0f - Pp[sl][c - 1];
    Sa[sl][0] = 1.0f;
#pragma unroll
    for (int c = 1; c < 16; ++c) Sa[sl][c] = Sa[sl][c - 1] * Hh[sl][c];
    sa15h0[sl] = Sa[sl][15] * Hh[sl][0];
  };

  // prologue: prefetch chunk 0 (storage rows 0..7) into Lb[0]
#pragma unroll
  for (int j = 0; j < CHUNK; ++j) {
#pragma unroll
    for (int sg = 0; sg < 4; ++sg) {
      glds16(Pz + ((size_t)j << 10) + (sg << 8) + (t << 2),
             &Lb[0][(j << 10) + (sg << 8)]);
    }
  }

  int cur = 0;
  for (int ck = 0; ck < NCHUNK; ++ck) {
    // wait for current chunk's glds (also drains old stores, once per chunk)
    asm volatile("s_waitcnt vmcnt(0)" ::: "memory");
    __builtin_amdgcn_sched_barrier(0);

    // issue prefetch of chunk ck+1 into the other buffer
    if (ck + 1 < NCHUNK) {
      const int s0n = (ck + 1) << 3;
      float* lb = &Lb[cur ^ 1][0];
#pragma unroll
      for (int j = 0; j < CHUNK; ++j) {
        const int row = (s0n + j) & 1023;
#pragma unroll
        for (int sg = 0; sg < 4; ++sg) {
          glds16(Pz + ((size_t)row << 10) + (sg << 8) + (t << 2),
                 lb + (j << 10) + (sg << 8));
        }
      }
    }

    // prime step-0 state (slot 0); prev p15 = last step of previous chunk
    precomp(0, &Lb[cur][col0], Pp[1][15]);

    const int s0 = ck << 3;
#pragma unroll
    for (int j = 0; j < CHUNK; ++j) {
      const int s = s0 + j;

      // THE serial cross-step op
      const float phiL = __shfl_up(phi15h, 1);

      // precompute next step's state (p prefetched -> H/SA/sa15h0 + early
      // pL shuffle). Off the critical path; j=7's successor is primed at
      // the next chunk top (its LDS rows aren't glds-safe yet).
      if (j < 7)
        precomp((j + 1) & 1, &Lb[cur][((j + 1) << 10) + col0], Pp[j & 1][15]);

      const int r = s - t;
      if (r >= 0 && r < 1024) {
        float* ph = Ph[j & 3];
        float phi15n;
        if (r == 0) {
#pragma unroll
          for (int c = 0; c < 16; ++c) ph[c] = 0.0f;
          if (t == 0) ph[0] = 1.0f;
          phi15n = ph[15];
        } else {
          // SB scan (parallel to the shuffle; depends only on b and Hh)
          float SBv[16];
          SBv[0] = b[0];
#pragma unroll
          for (int c = 1; c < 16; ++c)
            SBv[c] = fmaf(Hh[j & 1][c], SBv[c - 1], b[c]);
          // one fma after the shuffle -> next step's shuffle input
          phi15n = fmaf(sa15h0[j & 1], phiL, SBv[15]);
          const float phiIn = Hh[j & 1][0] * phiL;
#pragma unroll
          for (int c = 0; c < 15; ++c)
            ph[c] = fmaf(Sa[j & 1][c], phiIn, SBv[c]);
          ph[15] = phi15n;
        }
        // next-row carry + neighbor hold
#pragma unroll
        for (int c = 0; c < 16; ++c) b[c] = ph[c] * Pp[j & 1][c];
        phi15h = phi15n;
        // write phi over p's cells in global (in-place, coalesced). Ph's
        // 4-deep rotation keeps these VGPRs live ~3 steps past the store.
        float* spr = Pz + ((size_t)(s & 1023) << 10) + col0;
#pragma unroll
        for (int q = 0; q < 4; ++q)
          *(float4*)(spr + 4 * q) = *(float4*)&ph[4 * q];
      }
    }
    cur ^= 1;
  }
}

// ---------------------------------------------------------------------------
extern "C" void kernel_launch(void* const* d_in, const int* in_sizes, int n_in,
                              void* d_out, int out_size, void* d_ws, size_t ws_size,
                              hipStream_t stream)
{
  const float* query = (const float*)d_in[0];
  const float* key   = (const float*)d_in[1];
  const float* value = (const float*)d_in[2];
  const float* ipw   = (const float*)d_in[3];   // (1536,1024)
  const float* ipb   = (const float*)d_in[4];   // (1536,)
  const float* opw   = (const float*)d_in[5];   // (1024,1024)
  const float* opb   = (const float*)d_in[6];   // (1024,)
  float* out = (float*)d_out;
  float* ws  = (float*)d_ws;

  float* XQ  = ws + OFF_XQ;
  float* XK  = ws + OFF_XK;
  float* XVt = ws + OFF_XVT;
  float* XO  = ws + OFF_XO;
  float* P   = ws + OFF_P;

  // in-projections (MFMA bf16x3)
  gemm_nt_mfma_k<<<dim3(16, 32), 256, 0, stream>>>(
      query, 1024, ipw, 1024, ipb, XQ, 1024, 1024);
  gemm_nt_mfma_k<<<dim3(4, 32), 256, 0, stream>>>(
      key, 1024, ipw + (size_t)1024 * 1024, 1024, ipb + 1024, XK, 256, 1024);
  proj_vt_k<<<dim3(16, 4, 2), 256, 0, stream>>>(
      ipw + (size_t)1280 * 1024, value, ipb + 1280, XVt);

  // scores + sigmoid + clip -> P (diagonal layout)
  scores_mfma_k<<<dim3(16, 16, 32), 256, 0, stream>>>(XQ, XK, P);

  // monotonic recurrence in place (diagonal wavefront, LDS-chunked,
  // affine-split critical path, 4-deep store rotation)
  mono_rec_k<<<dim3(32), dim3(64), 0, stream>>>(P);

  // phi @ V -> XO (NT against transposed V; A read through diagonal map)
  pv_mfma_k<<<dim3(1, 16, 32), 256, 0, stream>>>(P, XVt, XO);

  // out-projection
  gemm_nt_mfma_k<<<dim3(16, 32), 256, 0, stream>>>(
      XO, 1024, opw, 1024, opb, out, 1024, 1024);
}

// Round 5
// 557.980 us; speedup vs baseline: 1.1931x; 1.1931x over previous
//
#include <hip/hip_runtime.h>
#include <cstddef>
#include <cstdint>

// Problem constants: EMBED=1024, NUM_HEADS=16, GQA=4, KV_HEADS=4,
// HEAD_DIM=64, KV_EMBED=256, EPS=1e-3, B=2, T=1024.
#define TSEQ 1024

typedef __attribute__((ext_vector_type(8))) short short8;   // 8 bf16 = 4 VGPRs
typedef __attribute__((ext_vector_type(4))) float floatx4;  // MFMA acc

// Workspace layout (floats):
//  XQ : 2048 x 1024  (2M)
//  XK : 2048 x 256   (0.5M)
//  XVt: 2 x 256 x 1024 (0.5M)  -- V-projection TRANSPOSED: [b][h*64+c][j]
//  XO : 2048 x 1024  (2M)
//  P  : 32 x 1024x1024 (33.55M) -- probs/phi in GROUP-DIAGONAL layout
static constexpr size_t OFF_XQ  = 0;
static constexpr size_t OFF_XK  = (size_t)2 * 1024 * 1024;
static constexpr size_t OFF_XVT = OFF_XK + (size_t)512 * 1024;
static constexpr size_t OFF_XO  = OFF_XVT + (size_t)512 * 1024;
static constexpr size_t OFF_P   = OFF_XO + (size_t)2 * 1024 * 1024;

// GROUP-DIAGONAL LAYOUT (R10): logical cell (r, c) lives at storage row
//   diagrow(r, c>>4) = (((r>>2) + (c>>4)) & 255)*4 + (r&3).
// The recurrence kernel processes R=4 rows per step: lane t owns cols
// [16t,16t+16) and at step s handles row-group g = s - t (rows 4g..4g+3).
// All 64 lanes' cells for one step live in ONE contiguous 16KB slot
// (slot = s & 255), read and overwritten in place. Wrap bijection: at step
// m the writers are lanes t <= m; at step m+256 the readers of that slot
// are lanes t >= m+1 -- disjoint. Scores (CDIAG) writes and PV (ADIAG)
// reads through the same map; per-instruction coalescing is preserved
// (the diag shift is constant within every 8-float staging segment and
// every 16-col store group).
//
// R10 rationale: R7/R8/R9 all measured ~750 cy/step (2.4GHz-normalized)
// despite wildly different per-step serial chains (16-fma vs 1-fma) and
// load paths (global vs LDS). A serial-chain model predicts ~250. The
// flat 3x multiplier across ALL variants (also retro-fits R0/R1) is an
// effective-clock effect: 32 near-idle single-wave blocks -> low DPM
// state (~800MHz). Therefore: amortize the per-step fixed cost (shuffle
// latency, loop, prefetch wait) over 4 rows/step; steps 1087 -> 319.

// ---------------------------------------------------------------------------
// fp32 -> bf16 hi/lo split (RNE). x ≈ hi + lo with residual ~2^-17 |x|.
// ---------------------------------------------------------------------------
__device__ __forceinline__ void cvt_hi_lo(float x, unsigned short& hi,
                                          unsigned short& lo) {
  unsigned u = __float_as_uint(x);
  unsigned rh = (u + 0x7FFFu + ((u >> 16) & 1u)) & 0xFFFF0000u;
  hi = (unsigned short)(rh >> 16);
  float xl = x - __uint_as_float(rh);
  unsigned ul = __float_as_uint(xl);
  unsigned rl = ul + 0x7FFFu + ((ul >> 16) & 1u);
  lo = (unsigned short)(rl >> 16);
}

__device__ __forceinline__ int diagrow(int r, int cblk) {
  return ((((r >> 2) + cblk) & 255) << 2) | (r & 3);
}

// ---------------------------------------------------------------------------
// Unified NT GEMM core, MFMA bf16x3 (R5-proven).
// ADIAG: A row index mapped through diagrow (reads group-diagonal matrix).
// CDIAG: C row index mapped through diagrow (writes group-diagonal matrix).
// ---------------------------------------------------------------------------
template <int EPI, int ADIAG, int CDIAG>
__device__ __forceinline__ void mfma_nt_core(
    const float* __restrict__ A, int lda,
    const float* __restrict__ B, int ldb,
    float* __restrict__ C, int ldc, int K,
    const float* __restrict__ bias)
{
  __shared__ __align__(16) unsigned short Ah[64][40];
  __shared__ __align__(16) unsigned short Al[64][40];
  __shared__ __align__(16) unsigned short Bh[64][40];
  __shared__ __align__(16) unsigned short Bl[64][40];

  const int bm = blockIdx.y << 6;
  const int bn = blockIdx.x << 6;
  const int tid  = threadIdx.x;
  const int lane = tid & 63;
  const int wave = tid >> 6;        // 0..3 -> row sub-tile
  const int m16  = lane & 15;
  const int quad = lane >> 4;

  const int srow = tid >> 2;        // staging: row 0..63
  const int skq  = (tid & 3) << 3;  // staging: k offset 0,8,16,24

  floatx4 acc[4];
#pragma unroll
  for (int c = 0; c < 4; ++c) acc[c] = (floatx4){0.f, 0.f, 0.f, 0.f};

  for (int k0 = 0; k0 < K; k0 += 32) {
    {
      const int kq = k0 + skq;
      int arow = bm + srow;
      if (ADIAG) arow = diagrow(arow, kq >> 4);
      const float* ap = A + (size_t)arow * lda + kq;
      const float* bp = B + (size_t)(bn + srow) * ldb + kq;
      float av[8] __attribute__((aligned(16)));
      float bv[8] __attribute__((aligned(16)));
      *(float4*)&av[0] = *(const float4*)(ap);
      *(float4*)&av[4] = *(const float4*)(ap + 4);
      *(float4*)&bv[0] = *(const float4*)(bp);
      *(float4*)&bv[4] = *(const float4*)(bp + 4);
      short8 vah, valo, vbh, vblo;
#pragma unroll
      for (int e = 0; e < 8; ++e) {
        unsigned short h, l;
        cvt_hi_lo(av[e], h, l);
        vah[e] = (short)h; valo[e] = (short)l;
        cvt_hi_lo(bv[e], h, l);
        vbh[e] = (short)h; vblo[e] = (short)l;
      }
      *(short8*)&Ah[srow][skq] = vah;
      *(short8*)&Al[srow][skq] = valo;
      *(short8*)&Bh[srow][skq] = vbh;
      *(short8*)&Bl[srow][skq] = vblo;
    }
    __syncthreads();

    const int arow = (wave << 4) + m16;
    const short8 a_h = *(const short8*)&Ah[arow][quad << 3];
    const short8 a_l = *(const short8*)&Al[arow][quad << 3];
#pragma unroll
    for (int c = 0; c < 4; ++c) {
      const int brow = (c << 4) + m16;
      const short8 b_h = *(const short8*)&Bh[brow][quad << 3];
      const short8 b_l = *(const short8*)&Bl[brow][quad << 3];
      acc[c] = __builtin_amdgcn_mfma_f32_16x16x32_bf16(a_h, b_h, acc[c], 0, 0, 0);
      acc[c] = __builtin_amdgcn_mfma_f32_16x16x32_bf16(a_h, b_l, acc[c], 0, 0, 0);
      acc[c] = __builtin_amdgcn_mfma_f32_16x16x32_bf16(a_l, b_h, acc[c], 0, 0, 0);
    }
    __syncthreads();
  }

#pragma unroll
  for (int c = 0; c < 4; ++c) {
#pragma unroll
    for (int r = 0; r < 4; ++r) {
      const int row = (wave << 4) + (quad << 2) + r;
      const int col = (c << 4) + m16;
      float v = acc[c][r];
      if (EPI == 0) { if (bias) v += bias[bn + col]; }
      if (EPI == 1) { v += bias[bm + row]; }
      if (EPI == 2) {
        v = 1.0f / (1.0f + expf(-v));
        v = fminf(fmaxf(v, 0.001f), 0.999f);
      }
      int crow = bm + row;
      if (CDIAG) crow = diagrow(crow, (bn + col) >> 4);
      C[(size_t)crow * ldc + (bn + col)] = v;
    }
  }
}

__global__ __launch_bounds__(256) void gemm_nt_mfma_k(
    const float* __restrict__ A, int lda, const float* __restrict__ W, int ldw,
    const float* __restrict__ bias, float* __restrict__ C, int ldc, int K)
{
  mfma_nt_core<0, 0, 0>(A, lda, W, ldw, C, ldc, K, bias);
}

__global__ __launch_bounds__(256) void proj_vt_k(
    const float* __restrict__ vw, const float* __restrict__ value,
    const float* __restrict__ vb, float* __restrict__ XVt)
{
  const int b = blockIdx.z;
  mfma_nt_core<1, 0, 0>(vw, 1024, value + ((size_t)b << 20), 1024,
                        XVt + (size_t)b * 256 * 1024, 1024, 1024, vb);
}

// scores: writes P in GROUP-DIAGONAL layout (CDIAG=1)
__global__ __launch_bounds__(256) void scores_mfma_k(
    const float* __restrict__ XQ, const float* __restrict__ XK,
    float* __restrict__ P)
{
  const int z = blockIdx.z;
  const int b = z >> 4;
  mfma_nt_core<2, 0, 1>(XQ + ((size_t)b << 20) + ((size_t)(z & 15) << 6), 1024,
                        XK + (size_t)b * TSEQ * 256 + ((size_t)(z & 3) << 6), 256,
                        P + ((size_t)z << 20), 1024, 64, nullptr);
}

// pv: reads phi (A matrix) from GROUP-DIAGONAL layout (ADIAG=1)
__global__ __launch_bounds__(256) void pv_mfma_k(
    const float* __restrict__ P, const float* __restrict__ XVt,
    float* __restrict__ XO)
{
  const int z = blockIdx.z;
  const int b = z >> 4;
  mfma_nt_core<0, 1, 0>(P + ((size_t)z << 20), 1024,
                        XVt + (size_t)b * 256 * 1024 + (size_t)(z & 3) * 64 * 1024, 1024,
                        XO + ((size_t)b << 20) + ((size_t)(z & 15) << 6), 1024,
                        1024, nullptr);
}

// ---------------------------------------------------------------------------
// Monotonic recurrence, 4-ROW diagonal wavefront (R10). ONE WAVE per z.
// Lane t owns cols [16t,16t+16); at step s handles row-group g = s - t
// (rows 4g..4g+3), direct recurrence:
//   phi[r,c] = b[c] + (1-p[r,c-1])*phi[r,c-1],  b[c] = phi[r-1,c]*p[r-1,c].
// Cross-lane: ONE batch of 8 __shfl_up(.,1) per step (phi15/p15 of the 4
// rows). b carries lane-locally between rows and steps. p for step s+1 is
// prefetched into registers at step s (ping-pong pA/pB, static indexing).
// Each step reads+writes one contiguous 16KB slot, in place.
// Cross-lane = __shfl only (DPP failed 3x on gfx950 -- permanently banned).
// ---------------------------------------------------------------------------
#define NSTEP 319   // 255 + 64 steps; loop padded to 320 (step 319 no-op)

__global__ __launch_bounds__(64) void mono_rec_k(float* __restrict__ P)
{
  const int z = blockIdx.x;
  float* __restrict__ Pz = P + ((size_t)z << 20);
  const int t = threadIdx.x;     // lane 0..63
  const int col0 = t << 4;       // first owned column

  float b[16];                   // carry: b[c] = phi[r-1,c] * p[r-1,c]
#pragma unroll
  for (int c = 0; c < 16; ++c) b[c] = 0.0f;
  float phi15h[4], p15h[4];      // col-15 values of the 4 rows, for lane t+1
#pragma unroll
  for (int k = 0; k < 4; ++k) { phi15h[k] = 0.0f; p15h[k] = 0.0f; }

  float pA[4][16], pB[4][16];    // p ping-pong (4 rows x 16 cols)

  // prologue: load slot 0 into pA
#pragma unroll
  for (int k = 0; k < 4; ++k) {
    const float* lp = Pz + (k << 10) + col0;
#pragma unroll
    for (int q = 0; q < 4; ++q)
      *(float4*)&pA[k][4 * q] = *(const float4*)(lp + 4 * q);
  }

  auto step = [&](int s, float (&pcur)[4][16], float (&pnext)[4][16]) {
    // prefetch next step's slot (never aliases in-flight stores: slots
    // s-1, s vs (s+1)&255 are distinct; wrap-overlap lanes are invalid)
    {
      const float* np = Pz + ((size_t)((s + 1) & 255) << 12) + col0;
#pragma unroll
      for (int k = 0; k < 4; ++k)
#pragma unroll
        for (int q = 0; q < 4; ++q)
          *(float4*)&pnext[k][4 * q] = *(const float4*)(np + (k << 10) + 4 * q);
    }

    // boundary batch from lane t-1 (its rows' col 16t-1, finished at s-1).
    // Unconditional so source lanes are active in the shuffle.
    float phiL[4], pL[4];
#pragma unroll
    for (int k = 0; k < 4; ++k) {
      phiL[k] = __shfl_up(phi15h[k], 1);
      pL[k]   = __shfl_up(p15h[k], 1);
    }

    const int g = s - t;
    if (g >= 0 && g < 256) {
      float* sp = Pz + ((size_t)(s & 255) << 12) + col0;
      float phi[16];
#pragma unroll
      for (int k = 0; k < 4; ++k) {
        const float* pk = pcur[k];
        if (g == 0 && k == 0) {
          // row 0: phi = onehot(col 0)
#pragma unroll
          for (int c = 0; c < 16; ++c) phi[c] = 0.0f;
          if (t == 0) phi[0] = 1.0f;
        } else {
          const float H0 = (t == 0) ? 0.0f : (1.0f - pL[k]);
          float x = fmaf(H0, phiL[k], b[0]);
          phi[0] = x;
#pragma unroll
          for (int c = 1; c < 16; ++c) {
            x = fmaf(1.0f - pk[c - 1], x, b[c]);
            phi[c] = x;
          }
        }
        // carry for next row + neighbor holds
#pragma unroll
        for (int c = 0; c < 16; ++c) b[c] = phi[c] * pk[c];
        p15h[k]   = pk[15];
        phi15h[k] = phi[15];
        // write phi over p's cells (in-place, coalesced)
#pragma unroll
        for (int q = 0; q < 4; ++q)
          *(float4*)(sp + (k << 10) + 4 * q) = *(float4*)&phi[4 * q];
      }
    }
  };

  for (int s0 = 0; s0 < 320; s0 += 2) {
    step(s0, pA, pB);
    step(s0 + 1, pB, pA);
  }
}

// ---------------------------------------------------------------------------
extern "C" void kernel_launch(void* const* d_in, const int* in_sizes, int n_in,
                              void* d_out, int out_size, void* d_ws, size_t ws_size,
                              hipStream_t stream)
{
  const float* query = (const float*)d_in[0];
  const float* key   = (const float*)d_in[1];
  const float* value = (const float*)d_in[2];
  const float* ipw   = (const float*)d_in[3];   // (1536,1024)
  const float* ipb   = (const float*)d_in[4];   // (1536,)
  const float* opw   = (const float*)d_in[5];   // (1024,1024)
  const float* opb   = (const float*)d_in[6];   // (1024,)
  float* out = (float*)d_out;
  float* ws  = (float*)d_ws;

  float* XQ  = ws + OFF_XQ;
  float* XK  = ws + OFF_XK;
  float* XVt = ws + OFF_XVT;
  float* XO  = ws + OFF_XO;
  float* P   = ws + OFF_P;

  // in-projections (MFMA bf16x3)
  gemm_nt_mfma_k<<<dim3(16, 32), 256, 0, stream>>>(
      query, 1024, ipw, 1024, ipb, XQ, 1024, 1024);
  gemm_nt_mfma_k<<<dim3(4, 32), 256, 0, stream>>>(
      key, 1024, ipw + (size_t)1024 * 1024, 1024, ipb + 1024, XK, 256, 1024);
  proj_vt_k<<<dim3(16, 4, 2), 256, 0, stream>>>(
      ipw + (size_t)1280 * 1024, value, ipb + 1280, XVt);

  // scores + sigmoid + clip -> P (group-diagonal layout)
  scores_mfma_k<<<dim3(16, 16, 32), 256, 0, stream>>>(XQ, XK, P);

  // monotonic recurrence in place (4-row diagonal wavefront, one wave per z)
  mono_rec_k<<<dim3(32), dim3(64), 0, stream>>>(P);

  // phi @ V -> XO (NT against transposed V; A read through diagonal map)
  pv_mfma_k<<<dim3(1, 16, 32), 256, 0, stream>>>(P, XVt, XO);

  // out-projection
  gemm_nt_mfma_k<<<dim3(16, 32), 256, 0, stream>>>(
      XO, 1024, opw, 1024, opb, out, 1024, 1024);
}

// Round 6
// 555.515 us; speedup vs baseline: 1.1984x; 1.0044x over previous
//
#include <hip/hip_runtime.h>
#include <cstddef>
#include <cstdint>

// Problem constants: EMBED=1024, NUM_HEADS=16, GQA=4, KV_HEADS=4,
// HEAD_DIM=64, KV_EMBED=256, EPS=1e-3, B=2, T=1024.
#define TSEQ 1024

typedef __attribute__((ext_vector_type(8))) short short8;   // 8 bf16 = 4 VGPRs
typedef __attribute__((ext_vector_type(4))) float floatx4;  // MFMA acc

// Workspace layout (floats):
//  XQ : 2048 x 1024  (2M)
//  XK : 2048 x 256   (0.5M)
//  XVt: 2 x 256 x 1024 (0.5M)  -- V-projection TRANSPOSED: [b][h*64+c][j]
//  XO : 2048 x 1024  (2M)
//  P  : 32 x 1024x1024 (33.55M) -- q=1-p / phi in GROUP-DIAGONAL layout
static constexpr size_t OFF_XQ  = 0;
static constexpr size_t OFF_XK  = (size_t)2 * 1024 * 1024;
static constexpr size_t OFF_XVT = OFF_XK + (size_t)512 * 1024;
static constexpr size_t OFF_XO  = OFF_XVT + (size_t)512 * 1024;
static constexpr size_t OFF_P   = OFF_XO + (size_t)2 * 1024 * 1024;

// GROUP-DIAGONAL LAYOUT (R10): logical cell (r, c) lives at storage row
//   diagrow(r, c>>4) = (((r>>2) + (c>>4)) & 255)*4 + (r&3).
// The recurrence kernel processes R=4 rows per step: lane t owns cols
// [16t,16t+16) and at step s handles row-group g = s - t (rows 4g..4g+3).
// All 64 lanes' cells for one step live in ONE contiguous 16KB slot
// (slot = s & 255), read and overwritten in place. Wrap bijection: at step
// m the writers are lanes t <= m; at step m+256 the readers of that slot
// are lanes t >= m+1 -- disjoint. Scores (CDIAG) writes and PV (ADIAG)
// reads through the same map; per-instruction coalescing is preserved.
//
// R11: scores stores q = 1 - p (= sigmoid(-x), clipped). Recurrence in q:
//   phi[r,c] = b[c] + q[r,c-1]*phi[r,c-1]        (chain fma, no sub)
//   b[c]     = phi[r,c]*p = fma(-q[r,c], phi, phi) (carry fma, no sub)
// Per-cell issue drops 3 ops -> 2, boundary subs vanish (H0 = qL).
// Model (calibrated on R=1/R=4): step = F + R*V, F~321cy, V: 409 -> ~285.
// R* = sqrt(16 F/V) ~ 4.2 -> R=4 stays optimal.

// ---------------------------------------------------------------------------
// fp32 -> bf16 hi/lo split (RNE). x ≈ hi + lo with residual ~2^-17 |x|.
// ---------------------------------------------------------------------------
__device__ __forceinline__ void cvt_hi_lo(float x, unsigned short& hi,
                                          unsigned short& lo) {
  unsigned u = __float_as_uint(x);
  unsigned rh = (u + 0x7FFFu + ((u >> 16) & 1u)) & 0xFFFF0000u;
  hi = (unsigned short)(rh >> 16);
  float xl = x - __uint_as_float(rh);
  unsigned ul = __float_as_uint(xl);
  unsigned rl = ul + 0x7FFFu + ((ul >> 16) & 1u);
  lo = (unsigned short)(rl >> 16);
}

__device__ __forceinline__ int diagrow(int r, int cblk) {
  return ((((r >> 2) + cblk) & 255) << 2) | (r & 3);
}

// ---------------------------------------------------------------------------
// Unified NT GEMM core, MFMA bf16x3 (R5-proven).
// ADIAG: A row index mapped through diagrow (reads group-diagonal matrix).
// CDIAG: C row index mapped through diagrow (writes group-diagonal matrix).
// EPI=2 writes q = sigmoid(-x) clipped (R11).
// ---------------------------------------------------------------------------
template <int EPI, int ADIAG, int CDIAG>
__device__ __forceinline__ void mfma_nt_core(
    const float* __restrict__ A, int lda,
    const float* __restrict__ B, int ldb,
    float* __restrict__ C, int ldc, int K,
    const float* __restrict__ bias)
{
  __shared__ __align__(16) unsigned short Ah[64][40];
  __shared__ __align__(16) unsigned short Al[64][40];
  __shared__ __align__(16) unsigned short Bh[64][40];
  __shared__ __align__(16) unsigned short Bl[64][40];

  const int bm = blockIdx.y << 6;
  const int bn = blockIdx.x << 6;
  const int tid  = threadIdx.x;
  const int lane = tid & 63;
  const int wave = tid >> 6;        // 0..3 -> row sub-tile
  const int m16  = lane & 15;
  const int quad = lane >> 4;

  const int srow = tid >> 2;        // staging: row 0..63
  const int skq  = (tid & 3) << 3;  // staging: k offset 0,8,16,24

  floatx4 acc[4];
#pragma unroll
  for (int c = 0; c < 4; ++c) acc[c] = (floatx4){0.f, 0.f, 0.f, 0.f};

  for (int k0 = 0; k0 < K; k0 += 32) {
    {
      const int kq = k0 + skq;
      int arow = bm + srow;
      if (ADIAG) arow = diagrow(arow, kq >> 4);
      const float* ap = A + (size_t)arow * lda + kq;
      const float* bp = B + (size_t)(bn + srow) * ldb + kq;
      float av[8] __attribute__((aligned(16)));
      float bv[8] __attribute__((aligned(16)));
      *(float4*)&av[0] = *(const float4*)(ap);
      *(float4*)&av[4] = *(const float4*)(ap + 4);
      *(float4*)&bv[0] = *(const float4*)(bp);
      *(float4*)&bv[4] = *(const float4*)(bp + 4);
      short8 vah, valo, vbh, vblo;
#pragma unroll
      for (int e = 0; e < 8; ++e) {
        unsigned short h, l;
        cvt_hi_lo(av[e], h, l);
        vah[e] = (short)h; valo[e] = (short)l;
        cvt_hi_lo(bv[e], h, l);
        vbh[e] = (short)h; vblo[e] = (short)l;
      }
      *(short8*)&Ah[srow][skq] = vah;
      *(short8*)&Al[srow][skq] = valo;
      *(short8*)&Bh[srow][skq] = vbh;
      *(short8*)&Bl[srow][skq] = vblo;
    }
    __syncthreads();

    const int arow = (wave << 4) + m16;
    const short8 a_h = *(const short8*)&Ah[arow][quad << 3];
    const short8 a_l = *(const short8*)&Al[arow][quad << 3];
#pragma unroll
    for (int c = 0; c < 4; ++c) {
      const int brow = (c << 4) + m16;
      const short8 b_h = *(const short8*)&Bh[brow][quad << 3];
      const short8 b_l = *(const short8*)&Bl[brow][quad << 3];
      acc[c] = __builtin_amdgcn_mfma_f32_16x16x32_bf16(a_h, b_h, acc[c], 0, 0, 0);
      acc[c] = __builtin_amdgcn_mfma_f32_16x16x32_bf16(a_h, b_l, acc[c], 0, 0, 0);
      acc[c] = __builtin_amdgcn_mfma_f32_16x16x32_bf16(a_l, b_h, acc[c], 0, 0, 0);
    }
    __syncthreads();
  }

#pragma unroll
  for (int c = 0; c < 4; ++c) {
#pragma unroll
    for (int r = 0; r < 4; ++r) {
      const int row = (wave << 4) + (quad << 2) + r;
      const int col = (c << 4) + m16;
      float v = acc[c][r];
      if (EPI == 0) { if (bias) v += bias[bn + col]; }
      if (EPI == 1) { v += bias[bm + row]; }
      if (EPI == 2) {
        // q = 1 - clip(sigmoid(v)) = clip(sigmoid(-v), 0.001, 0.999)
        v = 1.0f / (1.0f + expf(v));
        v = fminf(fmaxf(v, 0.001f), 0.999f);
      }
      int crow = bm + row;
      if (CDIAG) crow = diagrow(crow, (bn + col) >> 4);
      C[(size_t)crow * ldc + (bn + col)] = v;
    }
  }
}

__global__ __launch_bounds__(256) void gemm_nt_mfma_k(
    const float* __restrict__ A, int lda, const float* __restrict__ W, int ldw,
    const float* __restrict__ bias, float* __restrict__ C, int ldc, int K)
{
  mfma_nt_core<0, 0, 0>(A, lda, W, ldw, C, ldc, K, bias);
}

__global__ __launch_bounds__(256) void proj_vt_k(
    const float* __restrict__ vw, const float* __restrict__ value,
    const float* __restrict__ vb, float* __restrict__ XVt)
{
  const int b = blockIdx.z;
  mfma_nt_core<1, 0, 0>(vw, 1024, value + ((size_t)b << 20), 1024,
                        XVt + (size_t)b * 256 * 1024, 1024, 1024, vb);
}

// scores: writes q = 1-p in GROUP-DIAGONAL layout (CDIAG=1)
__global__ __launch_bounds__(256) void scores_mfma_k(
    const float* __restrict__ XQ, const float* __restrict__ XK,
    float* __restrict__ P)
{
  const int z = blockIdx.z;
  const int b = z >> 4;
  mfma_nt_core<2, 0, 1>(XQ + ((size_t)b << 20) + ((size_t)(z & 15) << 6), 1024,
                        XK + (size_t)b * TSEQ * 256 + ((size_t)(z & 3) << 6), 256,
                        P + ((size_t)z << 20), 1024, 64, nullptr);
}

// pv: reads phi (A matrix) from GROUP-DIAGONAL layout (ADIAG=1)
__global__ __launch_bounds__(256) void pv_mfma_k(
    const float* __restrict__ P, const float* __restrict__ XVt,
    float* __restrict__ XO)
{
  const int z = blockIdx.z;
  const int b = z >> 4;
  mfma_nt_core<0, 1, 0>(P + ((size_t)z << 20), 1024,
                        XVt + (size_t)b * 256 * 1024 + (size_t)(z & 3) * 64 * 1024, 1024,
                        XO + ((size_t)b << 20) + ((size_t)(z & 15) << 6), 1024,
                        1024, nullptr);
}

// ---------------------------------------------------------------------------
// Monotonic recurrence, 4-ROW diagonal wavefront in q-form (R11).
// ONE WAVE per z. Lane t owns cols [16t,16t+16); at step s handles row-group
// g = s - t (rows 4g..4g+3):
//   phi[r,c] = b[c] + q[r,c-1]*phi[r,c-1]   (1 fma)
//   b[c]     = fma(-q[r,c], phi[r,c], phi[r,c])  (= phi*p, 1 fma)
// Cross-lane: ONE batch of 8 __shfl_up(.,1) per step (phi15/q15 x 4 rows),
// issued at the top so their latency overlaps the prefetch issue. q for
// step s+1 prefetched into registers (ping-pong pA/pB, static indexing).
// Each step reads+writes one contiguous 16KB slot, in place.
// Cross-lane = __shfl only (DPP failed 3x on gfx950 -- permanently banned).
// ---------------------------------------------------------------------------
__global__ __launch_bounds__(64) void mono_rec_k(float* __restrict__ P)
{
  const int z = blockIdx.x;
  float* __restrict__ Pz = P + ((size_t)z << 20);
  const int t = threadIdx.x;     // lane 0..63
  const int col0 = t << 4;       // first owned column

  float b[16];                   // carry: b[c] = phi[r-1,c] * p[r-1,c]
#pragma unroll
  for (int c = 0; c < 16; ++c) b[c] = 0.0f;
  float phi15h[4], q15h[4];      // col-15 values of the 4 rows, for lane t+1
#pragma unroll
  for (int k = 0; k < 4; ++k) { phi15h[k] = 0.0f; q15h[k] = 0.0f; }

  float pA[4][16], pB[4][16];    // q ping-pong (4 rows x 16 cols)

  // prologue: load slot 0 into pA
#pragma unroll
  for (int k = 0; k < 4; ++k) {
    const float* lp = Pz + (k << 10) + col0;
#pragma unroll
    for (int q = 0; q < 4; ++q)
      *(float4*)&pA[k][4 * q] = *(const float4*)(lp + 4 * q);
  }

  auto step = [&](int s, float (&pcur)[4][16], float (&pnext)[4][16]) {
    // boundary batch from lane t-1 first (latency overlaps prefetch issue).
    // Unconditional so source lanes are active in the shuffle.
    float phiL[4], qL[4];
#pragma unroll
    for (int k = 0; k < 4; ++k) {
      phiL[k] = __shfl_up(phi15h[k], 1);
      qL[k]   = __shfl_up(q15h[k], 1);
    }

    // prefetch next step's slot (never aliases in-flight stores: slots
    // s-1, s vs (s+1)&255 are distinct; wrap-overlap lanes are invalid)
    {
      const float* np = Pz + ((size_t)((s + 1) & 255) << 12) + col0;
#pragma unroll
      for (int k = 0; k < 4; ++k)
#pragma unroll
        for (int q = 0; q < 4; ++q)
          *(float4*)&pnext[k][4 * q] = *(const float4*)(np + (k << 10) + 4 * q);
    }

    const int g = s - t;
    if (g >= 0 && g < 256) {
      float* sp = Pz + ((size_t)(s & 255) << 12) + col0;
      float phi[16];
#pragma unroll
      for (int k = 0; k < 4; ++k) {
        const float* qk = pcur[k];
        if (g == 0 && k == 0) {
          // row 0: phi = onehot(col 0)
#pragma unroll
          for (int c = 0; c < 16; ++c) phi[c] = 0.0f;
          if (t == 0) phi[0] = 1.0f;
        } else {
          const float H0 = (t == 0) ? 0.0f : qL[k];
          float x = fmaf(H0, phiL[k], b[0]);
          phi[0] = x;
#pragma unroll
          for (int c = 1; c < 16; ++c) {
            x = fmaf(qk[c - 1], x, b[c]);
            phi[c] = x;
          }
        }
        // carry for next row (b = phi*p = phi - q*phi) + neighbor holds
#pragma unroll
        for (int c = 0; c < 16; ++c) b[c] = fmaf(-qk[c], phi[c], phi[c]);
        q15h[k]   = qk[15];
        phi15h[k] = phi[15];
        // write phi over q's cells (in-place, coalesced)
#pragma unroll
        for (int q = 0; q < 4; ++q)
          *(float4*)(sp + (k << 10) + 4 * q) = *(float4*)&phi[4 * q];
      }
    }
  };

  for (int s0 = 0; s0 < 320; s0 += 2) {
    step(s0, pA, pB);
    step(s0 + 1, pB, pA);
  }
}

// ---------------------------------------------------------------------------
extern "C" void kernel_launch(void* const* d_in, const int* in_sizes, int n_in,
                              void* d_out, int out_size, void* d_ws, size_t ws_size,
                              hipStream_t stream)
{
  const float* query = (const float*)d_in[0];
  const float* key   = (const float*)d_in[1];
  const float* value = (const float*)d_in[2];
  const float* ipw   = (const float*)d_in[3];   // (1536,1024)
  const float* ipb   = (const float*)d_in[4];   // (1536,)
  const float* opw   = (const float*)d_in[5];   // (1024,1024)
  const float* opb   = (const float*)d_in[6];   // (1024,)
  float* out = (float*)d_out;
  float* ws  = (float*)d_ws;

  float* XQ  = ws + OFF_XQ;
  float* XK  = ws + OFF_XK;
  float* XVt = ws + OFF_XVT;
  float* XO  = ws + OFF_XO;
  float* P   = ws + OFF_P;

  // in-projections (MFMA bf16x3)
  gemm_nt_mfma_k<<<dim3(16, 32), 256, 0, stream>>>(
      query, 1024, ipw, 1024, ipb, XQ, 1024, 1024);
  gemm_nt_mfma_k<<<dim3(4, 32), 256, 0, stream>>>(
      key, 1024, ipw + (size_t)1024 * 1024, 1024, ipb + 1024, XK, 256, 1024);
  proj_vt_k<<<dim3(16, 4, 2), 256, 0, stream>>>(
      ipw + (size_t)1280 * 1024, value, ipb + 1280, XVt);

  // scores + sigmoid + clip -> q = 1-p (group-diagonal layout)
  scores_mfma_k<<<dim3(16, 16, 32), 256, 0, stream>>>(XQ, XK, P);

  // monotonic recurrence in place (4-row diagonal wavefront, q-form)
  mono_rec_k<<<dim3(32), dim3(64), 0, stream>>>(P);

  // phi @ V -> XO (NT against transposed V; A read through diagonal map)
  pv_mfma_k<<<dim3(1, 16, 32), 256, 0, stream>>>(P, XVt, XO);

  // out-projection
  gemm_nt_mfma_k<<<dim3(16, 32), 256, 0, stream>>>(
      XO, 1024, opw, 1024, opb, out, 1024, 1024);
}